// Round 10
// baseline (113.008 us; speedup 1.0000x reference)
//
#include <hip/hip_runtime.h>
#include <hip/hip_bf16.h>
#include <stdint.h>

// Problem constants
#define B_  4
#define S_  1024
#define D_  1024
#define H_  16
#define HD_ 64

using f32x4  = __attribute__((ext_vector_type(4))) float;
using bf16x8 = __attribute__((ext_vector_type(8))) __bf16;
using bf16x4 = __attribute__((ext_vector_type(4))) __bf16;
using f32x4v = __attribute__((ext_vector_type(4))) float;

// ---------------------------------------------------------------------------
// global -> LDS direct load, 16B per lane. LDS dest must be wave-uniform base;
// HW writes lane i at base + i*16 (m104).
__device__ __forceinline__ void g2l16(const void* g, void* l) {
  using gp = const __attribute__((address_space(1))) unsigned int*;
  using lp = __attribute__((address_space(3))) unsigned int*;
  __builtin_amdgcn_global_load_lds((gp)(unsigned long long)g,
                                   (lp)(unsigned int)(unsigned long long)l,
                                   16, 0, 0);
}

// ---------------------------------------------------------------------------
// prep: fused f32->bf16 cvt of X (blocks 0..4095), 4 weights (4096..8191),
// num_masked (8192), RoPE sin/cos table (8193..8321), qmul/kmul (8322).
// tab[p][d'] = (sin, cos) of p * 10000^(-d'/32), p in [0,1024], d' in [0,32).
__global__ __launch_bounds__(256)
void prep_kernel(const float* __restrict__ X, const float* __restrict__ w0,
                 const float* __restrict__ w1, const float* __restrict__ w2,
                 const float* __restrict__ w3, const unsigned char* __restrict__ mask,
                 const float* __restrict__ qsc, const float* __restrict__ ksc,
                 const float* __restrict__ pds,
                 __bf16* __restrict__ Xb, __bf16* __restrict__ Wqkv,
                 __bf16* __restrict__ Wob, int* __restrict__ nm,
                 float* __restrict__ tab, float* __restrict__ qmul,
                 float* __restrict__ kmul) {
  const int bid = blockIdx.x, tid = threadIdx.x;
  if (bid < 4096) {
    const int i = bid * 1024 + tid * 4;
    f32x4v v = *(const f32x4v*)(X + i);
    bf16x4 o;
    o[0] = (__bf16)v[0]; o[1] = (__bf16)v[1]; o[2] = (__bf16)v[2]; o[3] = (__bf16)v[3];
    *(bf16x4*)(Xb + i) = o;
  } else if (bid < 8192) {
    const int bid2 = bid - 4096;
    const int y = bid2 >> 10;
    const float* src = (y == 0) ? w0 : (y == 1) ? w1 : (y == 2) ? w2 : w3;
    __bf16* dst = (y < 3) ? (Wqkv + (size_t)y * 1048576) : Wob;
    const int i = (bid2 & 1023) * 1024 + tid * 4;
    f32x4v v = *(const f32x4v*)(src + i);
    bf16x4 o;
    o[0] = (__bf16)v[0]; o[1] = (__bf16)v[1]; o[2] = (__bf16)v[2]; o[3] = (__bf16)v[3];
    *(bf16x4*)(dst + i) = o;
  } else if (bid == 8192) {
    // one wave per batch: wave w sums mask[w][:]
    const int b = tid >> 6, ln = tid & 63;
    int s = 0;
    for (int i = ln; i < S_; i += 64) s += (mask[b * S_ + i] != 0) ? 1 : 0;
    #pragma unroll
    for (int k = 1; k < 64; k <<= 1) s += __shfl_xor(s, k);
    if (ln == 0) nm[b] = s;
  } else if (bid <= 8321) {
    // RoPE table: 1025 positions x 32 freqs
    const int idx = (bid - 8193) * 256 + tid;
    if (idx < 1025 * 32) {
      const int p = idx >> 5, d = idx & 31;
      const float ang = (float)p * exp2f((float)d * -0.41524101186092025f); // 10000^{-d/32}
      float sn, cs;
      sincosf(ang, &sn, &cs);
      tab[idx * 2]     = sn;
      tab[idx * 2 + 1] = cs;
    }
  } else {
    // combined per-dim multipliers (removes transcendentals from rope_rms)
    if (tid < 64) {
      qmul[tid] = qsc[tid] * 0.26017112262570096f * log1pf(expf(pds[tid]));
      kmul[tid] = ksc[tid];
    }
  }
}

// ---------------------------------------------------------------------------
// NT GEMM: C[M,N] = A[M,K] * B[N,K]^T, bf16 in, f32 acc.
// 128x128 tile, BK=32, prefetch double-buffered LDS, XOR bank swizzle.
// MODE 0: plain f32 C store (output projection).
// MODE 1: Q/K columns (col0 < 2048) store bf16 rows into Cbf[.,3072];
//         V columns (col0 >= 2048) store transposed into Vt[b,h,d,s].
template <int MODE>
__global__ __launch_bounds__(256)
void gemm_nt(const __bf16* __restrict__ A, const __bf16* __restrict__ Bm,
             float* __restrict__ Cf, __bf16* __restrict__ Cbf,
             __bf16* __restrict__ Vt, int N, int K) {
  __shared__ __bf16 sA[2][128 * 32];
  __shared__ __bf16 sB[2][128 * 32];
  const int tid = threadIdx.x;
  const int wv = tid >> 6, lane = tid & 63;
  const int row0 = blockIdx.y * 128, col0 = blockIdx.x * 128;
  const int wm = wv >> 1, wn = wv & 1;
  const int c0 = wv * 2, c1 = c0 + 1;
  const int srow = lane >> 2;                               // row within 16-row chunk
  const int scol = (((lane & 3) ^ ((lane >> 3) & 3))) * 8;  // swizzled source slot
  const __bf16* Ab = A + (size_t)(row0 + srow) * K + scol;
  const __bf16* Bb = Bm + (size_t)(col0 + srow) * K + scol;
  const int fr = lane & 15;
  const int fk = ((lane >> 4) ^ ((fr >> 1) & 3)) * 8;       // swizzled read col

  f32x4 acc[4][4] = {};

#define GSTAGE(buf, k0) do {                                              \
    g2l16(Ab + (size_t)(c0 * 16) * K + (k0), &sA[buf][c0 * 512]);         \
    g2l16(Ab + (size_t)(c1 * 16) * K + (k0), &sA[buf][c1 * 512]);         \
    g2l16(Bb + (size_t)(c0 * 16) * K + (k0), &sB[buf][c0 * 512]);         \
    g2l16(Bb + (size_t)(c1 * 16) * K + (k0), &sB[buf][c1 * 512]);         \
  } while (0)

  GSTAGE(0, 0);
  __syncthreads();
  int cur = 0;
  for (int k0 = 0; k0 < K; k0 += 32) {
    if (k0 + 32 < K) GSTAGE(cur ^ 1, k0 + 32);   // prefetch next tile

    bf16x8 af[4], bfr[4];
    #pragma unroll
    for (int m = 0; m < 4; ++m)
      af[m] = *(const bf16x8*)&sA[cur][(wm * 64 + m * 16 + fr) * 32 + fk];
    #pragma unroll
    for (int n = 0; n < 4; ++n)
      bfr[n] = *(const bf16x8*)&sB[cur][(wn * 64 + n * 16 + fr) * 32 + fk];

    #pragma unroll
    for (int m = 0; m < 4; ++m)
      #pragma unroll
      for (int n = 0; n < 4; ++n)
        acc[m][n] = __builtin_amdgcn_mfma_f32_16x16x32_bf16(af[m], bfr[n], acc[m][n], 0, 0, 0);

    __syncthreads();   // single barrier: drains prefetch vmcnt + protects buffers
    cur ^= 1;
  }
#undef GSTAGE

  const int g4 = (lane >> 4) * 4;
  if (MODE == 0) {
    #pragma unroll
    for (int m = 0; m < 4; ++m)
      #pragma unroll
      for (int n = 0; n < 4; ++n)
        #pragma unroll
        for (int r = 0; r < 4; ++r)
          Cf[(size_t)(row0 + wm * 64 + m * 16 + g4 + r) * N + col0 + wn * 64 + n * 16 + fr] =
              acc[m][n][r];
    return;
  }

  // ---- MODE 1 epilogues ----
  if (col0 >= 2048) {
    // V: transposed store into Vt[b][h][d][s]
    #pragma unroll
    for (int m = 0; m < 4; ++m) {
      const int row = row0 + wm * 64 + m * 16 + g4;   // = b*1024 + s (s%4==0)
      const int bq = row >> 10, s = row & 1023;
      #pragma unroll
      for (int n = 0; n < 4; ++n) {
        const int hd = col0 + wn * 64 + n * 16 + fr - 2048;  // h*64 + d
        bf16x4 ov;
        #pragma unroll
        for (int r = 0; r < 4; ++r) ov[r] = (__bf16)acc[m][n][r];
        *(bf16x4*)&Vt[(size_t)((bq * H_ + (hd >> 6)) * HD_ + (hd & 63)) * S_ + s] = ov;
      }
    }
  } else {
    // Q/K: plain bf16 row store into the QKV buffer (rope_rms consumes it)
    #pragma unroll
    for (int m = 0; m < 4; ++m)
      #pragma unroll
      for (int n = 0; n < 4; ++n)
        #pragma unroll
        for (int r = 0; r < 4; ++r)
          Cbf[(size_t)(row0 + wm * 64 + m * 16 + g4 + r) * N + col0 + wn * 64 + n * 16 + fr] =
              (__bf16)acc[m][n][r];
  }
}

// ---------------------------------------------------------------------------
// RoPE + RMSNorm v2: thread = (tensor, b, s, h, j). Thread owns dims
// [j*8, j*8+8) and [j*8+32, j*8+40) -- the RoPE pair (d, d+32) is IN-THREAD
// (no shuffles for rotation). RMS reduce: 2 shfls over the 4-lane j-group.
// No transcendentals (table + precomputed qmul/kmul). 2048 blocks x 256.
__global__ __launch_bounds__(256)
void rope_rms(const __bf16* __restrict__ QKV, __bf16* __restrict__ Qr,
              __bf16* __restrict__ Kr, const float* __restrict__ qmul,
              const float* __restrict__ kmul, const int* __restrict__ nm,
              const float* __restrict__ tab) {
  const int gt = blockIdx.x * 256 + threadIdx.x;
  const int j = gt & 3;
  const int h = (gt >> 2) & 15;
  const int s = (gt >> 6) & 1023;
  const int b = (gt >> 16) & 3;
  const bool isK = gt >= 262144;
  const int dlo = j * 8;

  const __bf16* src = QKV + (size_t)(b * S_ + s) * 3072 + (isK ? 1024 : 0) + h * HD_ + dlo;
  bf16x8 xl = *(const bf16x8*)src;           // dims dlo..dlo+7
  bf16x8 xh = *(const bf16x8*)(src + 32);    // dims dlo+32..dlo+39

  const int ip = s - nm[b];
  const int ap = ip < 0 ? -ip : ip;
  const float sgn = ip < 0 ? -1.f : 1.f;
  const float* trow = tab + (size_t)ap * 64 + dlo * 2;   // 8 (sin,cos) pairs
  f32x4v tv[4];
  #pragma unroll
  for (int k = 0; k < 4; ++k) tv[k] = *(const f32x4v*)(trow + k * 4);

  float ol[8], oh[8];
  float ss = 0.f;
  #pragma unroll
  for (int i = 0; i < 8; ++i) {
    const float fl = (float)xl[i];
    const float fh = (float)xh[i];
    const float sn = sgn * tv[i >> 1][(i & 1) * 2];
    const float cs = tv[i >> 1][(i & 1) * 2 + 1];
    ol[i] = fl * cs - fh * sn;
    oh[i] = fh * cs + fl * sn;
    ss += ol[i] * ol[i] + oh[i] * oh[i];
  }
  ss += __shfl_xor(ss, 1);
  ss += __shfl_xor(ss, 2);
  const float rn = rsqrtf(ss * (1.0f / 64.0f) + 1e-6f);

  const float* mul = isK ? kmul : qmul;
  f32x4v ml0 = *(const f32x4v*)(mul + dlo);
  f32x4v ml1 = *(const f32x4v*)(mul + dlo + 4);
  f32x4v mh0 = *(const f32x4v*)(mul + dlo + 32);
  f32x4v mh1 = *(const f32x4v*)(mul + dlo + 36);

  bf16x8 outl, outh;
  #pragma unroll
  for (int i = 0; i < 4; ++i) {
    outl[i]     = (__bf16)(ol[i] * rn * ml0[i]);
    outl[i + 4] = (__bf16)(ol[i + 4] * rn * ml1[i]);
    outh[i]     = (__bf16)(oh[i] * rn * mh0[i]);
    outh[i + 4] = (__bf16)(oh[i + 4] * rn * mh1[i]);
  }
  __bf16* dst = (isK ? Kr : Qr) + ((size_t)(b * H_ + h) * S_ + s) * HD_ + dlo;
  *(bf16x8*)dst = outl;
  *(bf16x8*)(dst + 32) = outh;
}

// ---------------------------------------------------------------------------
// Flash attention v6: block = 128 q rows (4 waves x 32 rows, m=0,1), grid 512
// (8 q-blocks x 64 bh, longest-first). Halves the tile count vs 64-row blocks
// (4608 vs 8704 stagings/barriers/softmax passes) while doubling MFMA per
// barrier (32). K/V LDS-staged (XOR swizzle) + prefetch dbuf; swapped QK^T
// keeps softmax in-lane; defer-max (THR=8). LDS 48KB.
__global__ __launch_bounds__(256)
void attn_fwd(const __bf16* __restrict__ Qr, const __bf16* __restrict__ Kr,
              const __bf16* __restrict__ Vt, __bf16* __restrict__ Ob,
              const int* __restrict__ nm) {
  const int bid = blockIdx.x;
  const int qblk = 7 - (bid >> 6);       // longest blocks dispatch first
  const int bh = bid & 63;
  const int b = bh >> 4, h = bh & 15;
  const int q0 = qblk * 128;
  const int tid = threadIdx.x, wv = tid >> 6, lane = tid & 63;

  __shared__ __bf16 sK[2][64 * 64];
  __shared__ __bf16 sV[2][64 * 64];
  __shared__ unsigned int sP[4][32 * 32];   // per-wave P^T, [q=32][32 words]

  const size_t bhs = (size_t)(b * H_ + h);
  const __bf16* Qh = Qr + bhs * (S_ * HD_);
  const __bf16* Kh = Kr + bhs * (S_ * HD_);
  const __bf16* Vh = Vt + bhs * (HD_ * S_);

  const int fr = lane & 15, g = lane >> 4;
  const int qbase = q0 + wv * 32;
  unsigned int* sPw = &sP[wv][0];
  const int swz = (fr & 7) << 2;            // sP word-XOR swizzle

  // Q fragments for both 16-row sub-tiles (held in registers all block)
  bf16x8 qf[2][2];
  #pragma unroll
  for (int m = 0; m < 2; ++m)
    #pragma unroll
    for (int ks = 0; ks < 2; ++ks)
      qf[m][ks] = *(const bf16x8*)&Qh[(size_t)(qbase + m * 16 + fr) * HD_ + ks * 32 + g * 8];

  f32x4 oacc[2][4] = {};                    // O^T rows d, col q_m
  float mrun[2] = {-3e38f, -3e38f}, lrun[2] = {0.f, 0.f};

  const int nmb = nm[b];
  const int srow = lane >> 3;
  const int ssw = ((lane & 7) ^ srow) * 8;  // inverse-swizzled source col
  const int c0 = wv * 2, c1 = c0 + 1;

#define ASTAGE(buf, kv) do {                                                    \
    g2l16(&Kh[(size_t)((kv) + c0 * 8 + srow) * HD_ + ssw], &sK[buf][c0 * 512]); \
    g2l16(&Kh[(size_t)((kv) + c1 * 8 + srow) * HD_ + ssw], &sK[buf][c1 * 512]); \
    g2l16(&Vh[(size_t)(c0 * 8 + srow) * S_ + (kv) + ssw], &sV[buf][c0 * 512]);  \
    g2l16(&Vh[(size_t)(c1 * 8 + srow) * S_ + (kv) + ssw], &sV[buf][c1 * 512]);  \
  } while (0)

  ASTAGE(0, 0);
  __syncthreads();
  int cur = 0;
  const int kvend = q0 + 128;

  for (int kv0 = 0; kv0 < kvend; kv0 += 64) {
    if (kv0 + 64 < kvend) ASTAGE(cur ^ 1, kv0 + 64);   // prefetch next tile

    // S^T = K Q^T : sacc[m][n][r] = S[qbase+m*16+fr][kv0 + n*16 + g*4 + r]
    f32x4 sacc[2][4] = {};
    __builtin_amdgcn_s_setprio(1);
    #pragma unroll
    for (int n = 0; n < 4; ++n) {
      const int krow = n * 16 + fr;
      #pragma unroll
      for (int ks = 0; ks < 2; ++ks) {
        bf16x8 kf = *(const bf16x8*)&sK[cur][krow * 64 + ((ks * 32 + g * 8) ^ ((krow & 7) * 8))];
        #pragma unroll
        for (int m = 0; m < 2; ++m)
          sacc[m][n] = __builtin_amdgcn_mfma_f32_16x16x32_bf16(kf, qf[m][ks], sacc[m][n], 0, 0, 0);
      }
    }
    __builtin_amdgcn_s_setprio(0);

    // mask: valid iff q >= kv && kv >= nmb (only the diagonal tiles diverge)
    const bool fullv = (qbase >= kv0 + 63) && (kv0 >= nmb);
    if (!fullv) {
      #pragma unroll
      for (int m = 0; m < 2; ++m) {
        const int q = qbase + m * 16 + fr;
        #pragma unroll
        for (int n = 0; n < 4; ++n)
          #pragma unroll
          for (int r = 0; r < 4; ++r) {
            const int kv = kv0 + n * 16 + g * 4 + r;
            if (q < kv || kv < nmb) sacc[m][n][r] = -1e30f;
          }
      }
    }

    // online softmax per m, defer-max: in-lane max + 2 shfls over g
    #pragma unroll
    for (int m = 0; m < 2; ++m) {
      float pmax = sacc[m][0][0];
      #pragma unroll
      for (int n = 0; n < 4; ++n)
        #pragma unroll
        for (int r = 0; r < 4; ++r) pmax = fmaxf(pmax, sacc[m][n][r]);
      pmax = fmaxf(pmax, __shfl_xor(pmax, 16));
      pmax = fmaxf(pmax, __shfl_xor(pmax, 32));
      if (pmax > mrun[m] + 8.f) {            // rescale only on big growth
        const float scl = exp2f(mrun[m] - pmax);
        lrun[m] *= scl;
        #pragma unroll
        for (int nd = 0; nd < 4; ++nd)
          #pragma unroll
          for (int r = 0; r < 4; ++r) oacc[m][nd][r] *= scl;
        mrun[m] = pmax;
      }
      float ls = 0.f;
      #pragma unroll
      for (int n = 0; n < 4; ++n)
        #pragma unroll
        for (int r = 0; r < 4; ++r) {
          const float p = exp2f(sacc[m][n][r] - mrun[m]);  // bounded by 2^8
          sacc[m][n][r] = p;
          ls += p;
        }
      ls += __shfl_xor(ls, 16);
      ls += __shfl_xor(ls, 32);
      lrun[m] += ls;
    }

    // pack P^T -> wave-private LDS (b64 writes, XOR swizzle), reload as frags
    #pragma unroll
    for (int m = 0; m < 2; ++m)
      #pragma unroll
      for (int n = 0; n < 4; ++n) {
        union { unsigned int u; __bf16 hh[2]; } p0, p1;
        p0.hh[0] = (__bf16)sacc[m][n][0]; p0.hh[1] = (__bf16)sacc[m][n][1];
        p1.hh[0] = (__bf16)sacc[m][n][2]; p1.hh[1] = (__bf16)sacc[m][n][3];
        const unsigned long long pu =
            (unsigned long long)p0.u | ((unsigned long long)p1.u << 32);
        *(unsigned long long*)&sPw[(m * 16 + fr) * 32 + ((n * 8 + g * 2) ^ swz)] = pu;
      }
    bf16x8 pf[2][2];
    #pragma unroll
    for (int m = 0; m < 2; ++m)
      #pragma unroll
      for (int ks = 0; ks < 2; ++ks)
        pf[m][ks] = *(const bf16x8*)&sPw[(m * 16 + fr) * 32 + ((ks * 16 + g * 4) ^ swz)];

    // O^T += V^T P^T
    __builtin_amdgcn_s_setprio(1);
    #pragma unroll
    for (int nd = 0; nd < 4; ++nd) {
      const int vrow = nd * 16 + fr;
      #pragma unroll
      for (int ks = 0; ks < 2; ++ks) {
        bf16x8 vf = *(const bf16x8*)&sV[cur][vrow * 64 + ((ks * 32 + g * 8) ^ ((vrow & 7) * 8))];
        #pragma unroll
        for (int m = 0; m < 2; ++m)
          oacc[m][nd] = __builtin_amdgcn_mfma_f32_16x16x32_bf16(vf, pf[m][ks], oacc[m][nd], 0, 0, 0);
      }
    }
    __builtin_amdgcn_s_setprio(0);

    __syncthreads();   // single barrier: drains prefetch + protects buffers
    cur ^= 1;
  }
#undef ASTAGE

  // normalize + write O rows (per m: 4 x 8B stores)
  #pragma unroll
  for (int m = 0; m < 2; ++m) {
    const float inv = 1.0f / lrun[m];
    const int q = qbase + m * 16 + fr;
    __bf16* orow = Ob + (size_t)(b * S_ + q) * D_ + h * HD_;
    #pragma unroll
    for (int nd = 0; nd < 4; ++nd) {
      bf16x4 ov;
      #pragma unroll
      for (int r = 0; r < 4; ++r) ov[r] = (__bf16)(oacc[m][nd][r] * inv);
      *(bf16x4*)&orow[nd * 16 + g * 4] = ov;
    }
  }
}

// ---------------------------------------------------------------------------
extern "C" void kernel_launch(void* const* d_in, const int* in_sizes, int n_in,
                              void* d_out, int out_size, void* d_ws, size_t ws_size,
                              hipStream_t stream) {
  (void)in_sizes; (void)n_in; (void)out_size; (void)ws_size;
  const float* X  = (const float*)d_in[0];
  const unsigned char* pm = (const unsigned char*)d_in[1];
  const float* Wq = (const float*)d_in[2];
  const float* Wk = (const float*)d_in[3];
  const float* Wv = (const float*)d_in[4];
  const float* Wo = (const float*)d_in[5];
  const float* qs = (const float*)d_in[6];
  const float* ks = (const float*)d_in[7];
  const float* pd = (const float*)d_in[8];
  float* out = (float*)d_out;

  char* ws = (char*)d_ws;
  int*    nm   = (int*)ws;                               // [0, 256)
  __bf16* Wqkv = (__bf16*)(ws + 256);                    // 3072x1024 (6MB)
  __bf16* Wob  = (__bf16*)(ws + 256 + 6291456);          // 1024x1024 (2MB)
  __bf16* Xb   = (__bf16*)(ws + 8388864);                // 4096x1024 (8MB)
  __bf16* QKV  = (__bf16*)(ws + 16777472);               // 4096x3072 (24MB, V cols unused)
  __bf16* Krb  = (__bf16*)(ws + 41943296);               // [b,h,s,d] (8MB)
  __bf16* Vtb  = (__bf16*)(ws + 50331904);               // [b,h,d,s] (8MB)
  float*  tab  = (float*)(ws + 58720512);                // RoPE table (256.25KB)
  float*  qmul = (float*)(ws + 58982912);                // 64 floats
  float*  kmul = (float*)(ws + 58983168);                // 64 floats
  __bf16* Qrb  = Xb;                                     // alias (Xb dead after gemm1)
  __bf16* Obuf = QKV;                                    // alias (QKV dead after rope)

  prep_kernel<<<8323, 256, 0, stream>>>(X, Wq, Wk, Wv, Wo, pm, qs, ks, pd,
                                        Xb, Wqkv, Wob, nm, tab, qmul, kmul);

  // QKV projection; Q/K rows -> QKV buffer, V -> transposed Vtb
  gemm_nt<1><<<dim3(24, 32), 256, 0, stream>>>(Xb, Wqkv, nullptr, QKV, Vtb, 3072, 1024);

  rope_rms<<<2048, 256, 0, stream>>>(QKV, Qrb, Krb, qmul, kmul, nm, tab);

  attn_fwd<<<512, 256, 0, stream>>>(Qrb, Krb, Vtb, Obuf, nm);

  // out = Obuf @ Wo^T  (M=4096, N=1024, K=1024)
  gemm_nt<0><<<dim3(8, 32), 256, 0, stream>>>(Obuf, Wob, out, nullptr, nullptr, 1024, 1024);
}

// Round 11
// 102.388 us; speedup vs baseline: 1.1037x; 1.1037x over previous
//
#include <hip/hip_runtime.h>
#include <hip/hip_bf16.h>
#include <stdint.h>

// Problem constants
#define B_  4
#define S_  1024
#define D_  1024
#define H_  16
#define HD_ 64

using f32x4  = __attribute__((ext_vector_type(4))) float;
using bf16x8 = __attribute__((ext_vector_type(8))) __bf16;
using bf16x4 = __attribute__((ext_vector_type(4))) __bf16;
using f32x4v = __attribute__((ext_vector_type(4))) float;

// ---------------------------------------------------------------------------
// global -> LDS direct load, 16B per lane. LDS dest must be wave-uniform base;
// HW writes lane i at base + i*16 (m104).
__device__ __forceinline__ void g2l16(const void* g, void* l) {
  using gp = const __attribute__((address_space(1))) unsigned int*;
  using lp = __attribute__((address_space(3))) unsigned int*;
  __builtin_amdgcn_global_load_lds((gp)(unsigned long long)g,
                                   (lp)(unsigned int)(unsigned long long)l,
                                   16, 0, 0);
}

// ---------------------------------------------------------------------------
// prep: fused f32->bf16 cvt of X (blocks 0..4095), 4 weights (4096..8191),
// num_masked (8192), RoPE sin/cos table (8193..8321), qmul/kmul (8322).
// tab[p][d'] = (sin, cos) of p * 10000^(-d'/32), p in [0,1024], d' in [0,32).
__global__ __launch_bounds__(256)
void prep_kernel(const float* __restrict__ X, const float* __restrict__ w0,
                 const float* __restrict__ w1, const float* __restrict__ w2,
                 const float* __restrict__ w3, const unsigned char* __restrict__ mask,
                 const float* __restrict__ qsc, const float* __restrict__ ksc,
                 const float* __restrict__ pds,
                 __bf16* __restrict__ Xb, __bf16* __restrict__ Wqkv,
                 __bf16* __restrict__ Wob, int* __restrict__ nm,
                 float* __restrict__ tab, float* __restrict__ qmul,
                 float* __restrict__ kmul) {
  const int bid = blockIdx.x, tid = threadIdx.x;
  if (bid < 4096) {
    const int i = bid * 1024 + tid * 4;
    f32x4v v = *(const f32x4v*)(X + i);
    bf16x4 o;
    o[0] = (__bf16)v[0]; o[1] = (__bf16)v[1]; o[2] = (__bf16)v[2]; o[3] = (__bf16)v[3];
    *(bf16x4*)(Xb + i) = o;
  } else if (bid < 8192) {
    const int bid2 = bid - 4096;
    const int y = bid2 >> 10;
    const float* src = (y == 0) ? w0 : (y == 1) ? w1 : (y == 2) ? w2 : w3;
    __bf16* dst = (y < 3) ? (Wqkv + (size_t)y * 1048576) : Wob;
    const int i = (bid2 & 1023) * 1024 + tid * 4;
    f32x4v v = *(const f32x4v*)(src + i);
    bf16x4 o;
    o[0] = (__bf16)v[0]; o[1] = (__bf16)v[1]; o[2] = (__bf16)v[2]; o[3] = (__bf16)v[3];
    *(bf16x4*)(dst + i) = o;
  } else if (bid == 8192) {
    // one wave per batch: wave w sums mask[w][:]
    const int b = tid >> 6, ln = tid & 63;
    int s = 0;
    for (int i = ln; i < S_; i += 64) s += (mask[b * S_ + i] != 0) ? 1 : 0;
    #pragma unroll
    for (int k = 1; k < 64; k <<= 1) s += __shfl_xor(s, k);
    if (ln == 0) nm[b] = s;
  } else if (bid <= 8321) {
    // RoPE table: 1025 positions x 32 freqs
    const int idx = (bid - 8193) * 256 + tid;
    if (idx < 1025 * 32) {
      const int p = idx >> 5, d = idx & 31;
      const float ang = (float)p * exp2f((float)d * -0.41524101186092025f); // 10000^{-d/32}
      float sn, cs;
      sincosf(ang, &sn, &cs);
      tab[idx * 2]     = sn;
      tab[idx * 2 + 1] = cs;
    }
  } else {
    // combined per-dim multipliers (removes transcendentals from rope_rms)
    if (tid < 64) {
      qmul[tid] = qsc[tid] * 0.26017112262570096f * log1pf(expf(pds[tid]));
      kmul[tid] = ksc[tid];
    }
  }
}

// ---------------------------------------------------------------------------
// NT GEMM: C[M,N] = A[M,K] * B[N,K]^T, bf16 in, f32 acc.
// 128x128 tile, BK=32, prefetch double-buffered LDS, XOR bank swizzle,
// bijective XCD-chunk block swizzle (T1; nwg%8==0 for both call sites).
// MODE 0: plain f32 C store (output projection).
// MODE 1: Q/K columns (col0 < 2048) store bf16 rows into Cbf[.,3072];
//         V columns (col0 >= 2048) store transposed into Vt[b,h,d,s].
template <int MODE>
__global__ __launch_bounds__(256)
void gemm_nt(const __bf16* __restrict__ A, const __bf16* __restrict__ Bm,
             float* __restrict__ Cf, __bf16* __restrict__ Cbf,
             __bf16* __restrict__ Vt, int N, int K) {
  __shared__ __bf16 sA[2][128 * 32];
  __shared__ __bf16 sB[2][128 * 32];
  const int tid = threadIdx.x;
  const int wv = tid >> 6, lane = tid & 63;

  // XCD-chunk swizzle: give each XCD a contiguous chunk of the grid so
  // neighboring tiles (sharing A row-panels / B col-panels) share one L2.
  const int nwg = gridDim.x * gridDim.y;               // 768 / 256, %8 == 0
  const int lin = blockIdx.y * gridDim.x + blockIdx.x;
  const int swzid = (lin & 7) * (nwg >> 3) + (lin >> 3);
  const int row0 = (swzid / gridDim.x) * 128;
  const int col0 = (swzid % gridDim.x) * 128;

  const int wm = wv >> 1, wn = wv & 1;
  const int c0 = wv * 2, c1 = c0 + 1;
  const int srow = lane >> 2;                               // row within 16-row chunk
  const int scol = (((lane & 3) ^ ((lane >> 3) & 3))) * 8;  // swizzled source slot
  const __bf16* Ab = A + (size_t)(row0 + srow) * K + scol;
  const __bf16* Bb = Bm + (size_t)(col0 + srow) * K + scol;
  const int fr = lane & 15;
  const int fk = ((lane >> 4) ^ ((fr >> 1) & 3)) * 8;       // swizzled read col

  f32x4 acc[4][4] = {};

#define GSTAGE(buf, k0) do {                                              \
    g2l16(Ab + (size_t)(c0 * 16) * K + (k0), &sA[buf][c0 * 512]);         \
    g2l16(Ab + (size_t)(c1 * 16) * K + (k0), &sA[buf][c1 * 512]);         \
    g2l16(Bb + (size_t)(c0 * 16) * K + (k0), &sB[buf][c0 * 512]);         \
    g2l16(Bb + (size_t)(c1 * 16) * K + (k0), &sB[buf][c1 * 512]);         \
  } while (0)

  GSTAGE(0, 0);
  __syncthreads();
  int cur = 0;
  for (int k0 = 0; k0 < K; k0 += 32) {
    if (k0 + 32 < K) GSTAGE(cur ^ 1, k0 + 32);   // prefetch next tile

    bf16x8 af[4], bfr[4];
    #pragma unroll
    for (int m = 0; m < 4; ++m)
      af[m] = *(const bf16x8*)&sA[cur][(wm * 64 + m * 16 + fr) * 32 + fk];
    #pragma unroll
    for (int n = 0; n < 4; ++n)
      bfr[n] = *(const bf16x8*)&sB[cur][(wn * 64 + n * 16 + fr) * 32 + fk];

    #pragma unroll
    for (int m = 0; m < 4; ++m)
      #pragma unroll
      for (int n = 0; n < 4; ++n)
        acc[m][n] = __builtin_amdgcn_mfma_f32_16x16x32_bf16(af[m], bfr[n], acc[m][n], 0, 0, 0);

    __syncthreads();   // single barrier: drains prefetch vmcnt + protects buffers
    cur ^= 1;
  }
#undef GSTAGE

  const int g4 = (lane >> 4) * 4;
  if (MODE == 0) {
    #pragma unroll
    for (int m = 0; m < 4; ++m)
      #pragma unroll
      for (int n = 0; n < 4; ++n)
        #pragma unroll
        for (int r = 0; r < 4; ++r)
          Cf[(size_t)(row0 + wm * 64 + m * 16 + g4 + r) * N + col0 + wn * 64 + n * 16 + fr] =
              acc[m][n][r];
    return;
  }

  // ---- MODE 1 epilogues ----
  if (col0 >= 2048) {
    // V: transposed store into Vt[b][h][d][s]
    #pragma unroll
    for (int m = 0; m < 4; ++m) {
      const int row = row0 + wm * 64 + m * 16 + g4;   // = b*1024 + s (s%4==0)
      const int bq = row >> 10, s = row & 1023;
      #pragma unroll
      for (int n = 0; n < 4; ++n) {
        const int hd = col0 + wn * 64 + n * 16 + fr - 2048;  // h*64 + d
        bf16x4 ov;
        #pragma unroll
        for (int r = 0; r < 4; ++r) ov[r] = (__bf16)acc[m][n][r];
        *(bf16x4*)&Vt[(size_t)((bq * H_ + (hd >> 6)) * HD_ + (hd & 63)) * S_ + s] = ov;
      }
    }
  } else {
    // Q/K: plain bf16 row store into the QKV buffer (rope_rms consumes it)
    #pragma unroll
    for (int m = 0; m < 4; ++m)
      #pragma unroll
      for (int n = 0; n < 4; ++n)
        #pragma unroll
        for (int r = 0; r < 4; ++r)
          Cbf[(size_t)(row0 + wm * 64 + m * 16 + g4 + r) * N + col0 + wn * 64 + n * 16 + fr] =
              (__bf16)acc[m][n][r];
  }
}

// ---------------------------------------------------------------------------
// RoPE + RMSNorm v2: thread = (tensor, b, s, h, j). Thread owns dims
// [j*8, j*8+8) and [j*8+32, j*8+40) -- the RoPE pair (d, d+32) is IN-THREAD
// (no shuffles for rotation). RMS reduce: 2 shfls over the 4-lane j-group.
// No transcendentals (table + precomputed qmul/kmul). 2048 blocks x 256.
__global__ __launch_bounds__(256)
void rope_rms(const __bf16* __restrict__ QKV, __bf16* __restrict__ Qr,
              __bf16* __restrict__ Kr, const float* __restrict__ qmul,
              const float* __restrict__ kmul, const int* __restrict__ nm,
              const float* __restrict__ tab) {
  const int gt = blockIdx.x * 256 + threadIdx.x;
  const int j = gt & 3;
  const int h = (gt >> 2) & 15;
  const int s = (gt >> 6) & 1023;
  const int b = (gt >> 16) & 3;
  const bool isK = gt >= 262144;
  const int dlo = j * 8;

  const __bf16* src = QKV + (size_t)(b * S_ + s) * 3072 + (isK ? 1024 : 0) + h * HD_ + dlo;
  bf16x8 xl = *(const bf16x8*)src;           // dims dlo..dlo+7
  bf16x8 xh = *(const bf16x8*)(src + 32);    // dims dlo+32..dlo+39

  const int ip = s - nm[b];
  const int ap = ip < 0 ? -ip : ip;
  const float sgn = ip < 0 ? -1.f : 1.f;
  const float* trow = tab + (size_t)ap * 64 + dlo * 2;   // 8 (sin,cos) pairs
  f32x4v tv[4];
  #pragma unroll
  for (int k = 0; k < 4; ++k) tv[k] = *(const f32x4v*)(trow + k * 4);

  float ol[8], oh[8];
  float ss = 0.f;
  #pragma unroll
  for (int i = 0; i < 8; ++i) {
    const float fl = (float)xl[i];
    const float fh = (float)xh[i];
    const float sn = sgn * tv[i >> 1][(i & 1) * 2];
    const float cs = tv[i >> 1][(i & 1) * 2 + 1];
    ol[i] = fl * cs - fh * sn;
    oh[i] = fh * cs + fl * sn;
    ss += ol[i] * ol[i] + oh[i] * oh[i];
  }
  ss += __shfl_xor(ss, 1);
  ss += __shfl_xor(ss, 2);
  const float rn = rsqrtf(ss * (1.0f / 64.0f) + 1e-6f);

  const float* mul = isK ? kmul : qmul;
  f32x4v ml0 = *(const f32x4v*)(mul + dlo);
  f32x4v ml1 = *(const f32x4v*)(mul + dlo + 4);
  f32x4v mh0 = *(const f32x4v*)(mul + dlo + 32);
  f32x4v mh1 = *(const f32x4v*)(mul + dlo + 36);

  bf16x8 outl, outh;
  #pragma unroll
  for (int i = 0; i < 4; ++i) {
    outl[i]     = (__bf16)(ol[i] * rn * ml0[i]);
    outl[i + 4] = (__bf16)(ol[i + 4] * rn * ml1[i]);
    outh[i]     = (__bf16)(oh[i] * rn * mh0[i]);
    outh[i + 4] = (__bf16)(oh[i + 4] * rn * mh1[i]);
  }
  __bf16* dst = (isK ? Kr : Qr) + ((size_t)(b * H_ + h) * S_ + s) * HD_ + dlo;
  *(bf16x8*)dst = outl;
  *(bf16x8*)(dst + 32) = outh;
}

// ---------------------------------------------------------------------------
// Flash attention (round-9 structure, the measured sweet spot): block = 64 q
// rows (4 waves x 16), grid 1024 (longest-first), K/V LDS-staged via
// global_load_lds with XOR swizzle, prefetch double-buffer, one barrier per
// tile. Swapped QK^T (S^T = K Q^T) keeps softmax in-lane; defer-max (THR=8).
// NOTE: 128-row blocks (grid 512) measured WORSE (48us, occupancy 13%) --
// this structure needs 4 blocks/CU of TLP more than per-tile amortization.
__global__ __launch_bounds__(256)
void attn_fwd(const __bf16* __restrict__ Qr, const __bf16* __restrict__ Kr,
              const __bf16* __restrict__ Vt, __bf16* __restrict__ Ob,
              const int* __restrict__ nm) {
  const int bid = blockIdx.x;
  const int qblk = 15 - (bid >> 6);      // longest blocks dispatch first
  const int bh = bid & 63;
  const int b = bh >> 4, h = bh & 15;
  const int q0 = qblk * 64;
  const int tid = threadIdx.x, wv = tid >> 6, lane = tid & 63;

  __shared__ __bf16 sK[2][64 * 64];
  __shared__ __bf16 sV[2][64 * 64];
  __shared__ unsigned int sP[4][16 * 32];   // per-wave P^T, [q=16][32 words]

  const size_t bhs = (size_t)(b * H_ + h);
  const __bf16* Qh = Qr + bhs * (S_ * HD_);
  const __bf16* Kh = Kr + bhs * (S_ * HD_);
  const __bf16* Vh = Vt + bhs * (HD_ * S_);

  const int fr = lane & 15, g = lane >> 4;
  const int qbase = q0 + wv * 16;
  const int q = qbase + fr;                 // this lane's q-row
  unsigned int* sPw = &sP[wv][0];
  const int swz = (fr & 7) << 2;            // sP word-XOR swizzle

  bf16x8 qf[2];
  #pragma unroll
  for (int ks = 0; ks < 2; ++ks)
    qf[ks] = *(const bf16x8*)&Qh[(size_t)q * HD_ + ks * 32 + g * 8];

  f32x4 oacc[4] = {};                       // O^T: row d = nd*16+g*4+r, col q
  float mrun = -3e38f, lrun = 0.f;

  const int nmb = nm[b];
  const int srow = lane >> 3;
  const int ssw = ((lane & 7) ^ srow) * 8;  // inverse-swizzled source col
  const int c0 = wv * 2, c1 = c0 + 1;

#define ASTAGE(buf, kv) do {                                                    \
    g2l16(&Kh[(size_t)((kv) + c0 * 8 + srow) * HD_ + ssw], &sK[buf][c0 * 512]); \
    g2l16(&Kh[(size_t)((kv) + c1 * 8 + srow) * HD_ + ssw], &sK[buf][c1 * 512]); \
    g2l16(&Vh[(size_t)(c0 * 8 + srow) * S_ + (kv) + ssw], &sV[buf][c0 * 512]);  \
    g2l16(&Vh[(size_t)(c1 * 8 + srow) * S_ + (kv) + ssw], &sV[buf][c1 * 512]);  \
  } while (0)

  ASTAGE(0, 0);
  __syncthreads();
  int cur = 0;
  const int kvend = q0 + 64;

  for (int kv0 = 0; kv0 < kvend; kv0 += 64) {
    if (kv0 + 64 < kvend) ASTAGE(cur ^ 1, kv0 + 64);   // prefetch next tile

    // S^T = K Q^T : sacc[n][r] = S[q][kv0 + n*16 + g*4 + r]
    f32x4 sacc[4] = {};
    __builtin_amdgcn_s_setprio(1);
    #pragma unroll
    for (int n = 0; n < 4; ++n) {
      const int krow = n * 16 + fr;
      #pragma unroll
      for (int ks = 0; ks < 2; ++ks) {
        bf16x8 kf = *(const bf16x8*)&sK[cur][krow * 64 + ((ks * 32 + g * 8) ^ ((krow & 7) * 8))];
        sacc[n] = __builtin_amdgcn_mfma_f32_16x16x32_bf16(kf, qf[ks], sacc[n], 0, 0, 0);
      }
    }
    __builtin_amdgcn_s_setprio(0);

    // mask: valid iff q >= kv && kv >= nmb (only the diagonal tile diverges)
    const bool fullv = (qbase >= kv0 + 63) && (kv0 >= nmb);
    if (!fullv) {
      #pragma unroll
      for (int n = 0; n < 4; ++n)
        #pragma unroll
        for (int r = 0; r < 4; ++r) {
          const int kv = kv0 + n * 16 + g * 4 + r;
          if (q < kv || kv < nmb) sacc[n][r] = -1e30f;
        }
    }

    // online softmax, defer-max: in-lane max + 2 shfls over g
    float pmax = sacc[0][0];
    #pragma unroll
    for (int n = 0; n < 4; ++n)
      #pragma unroll
      for (int r = 0; r < 4; ++r) pmax = fmaxf(pmax, sacc[n][r]);
    pmax = fmaxf(pmax, __shfl_xor(pmax, 16));
    pmax = fmaxf(pmax, __shfl_xor(pmax, 32));
    if (pmax > mrun + 8.f) {                 // rescale only on big growth
      const float scl = exp2f(mrun - pmax);
      lrun *= scl;
      #pragma unroll
      for (int nd = 0; nd < 4; ++nd)
        #pragma unroll
        for (int r = 0; r < 4; ++r) oacc[nd][r] *= scl;
      mrun = pmax;
    }
    float ls = 0.f;
    #pragma unroll
    for (int n = 0; n < 4; ++n)
      #pragma unroll
      for (int r = 0; r < 4; ++r) {
        const float p = exp2f(sacc[n][r] - mrun);   // bounded by 2^8
        sacc[n][r] = p;
        ls += p;
      }
    ls += __shfl_xor(ls, 16);
    ls += __shfl_xor(ls, 32);
    lrun += ls;

    // pack P^T -> wave-private LDS (b64 writes, XOR swizzle), reload as frags
    #pragma unroll
    for (int n = 0; n < 4; ++n) {
      union { unsigned int u; __bf16 hh[2]; } p0, p1;
      p0.hh[0] = (__bf16)sacc[n][0]; p0.hh[1] = (__bf16)sacc[n][1];
      p1.hh[0] = (__bf16)sacc[n][2]; p1.hh[1] = (__bf16)sacc[n][3];
      const unsigned long long pu =
          (unsigned long long)p0.u | ((unsigned long long)p1.u << 32);
      *(unsigned long long*)&sPw[fr * 32 + ((n * 8 + g * 2) ^ swz)] = pu;
    }
    bf16x8 pf[2];
    #pragma unroll
    for (int ks = 0; ks < 2; ++ks)
      pf[ks] = *(const bf16x8*)&sPw[fr * 32 + ((ks * 16 + g * 4) ^ swz)];

    // O^T += V^T P^T
    __builtin_amdgcn_s_setprio(1);
    #pragma unroll
    for (int nd = 0; nd < 4; ++nd) {
      const int vrow = nd * 16 + fr;
      #pragma unroll
      for (int ks = 0; ks < 2; ++ks) {
        bf16x8 vf = *(const bf16x8*)&sV[cur][vrow * 64 + ((ks * 32 + g * 8) ^ ((vrow & 7) * 8))];
        oacc[nd] = __builtin_amdgcn_mfma_f32_16x16x32_bf16(vf, pf[ks], oacc[nd], 0, 0, 0);
      }
    }
    __builtin_amdgcn_s_setprio(0);

    __syncthreads();   // single barrier: drains prefetch + protects buffers
    cur ^= 1;
  }
#undef ASTAGE

  // normalize + write O row q (4 x 8B stores)
  const float inv = 1.0f / lrun;
  __bf16* orow = Ob + (size_t)(b * S_ + q) * D_ + h * HD_;
  #pragma unroll
  for (int nd = 0; nd < 4; ++nd) {
    bf16x4 ov;
    #pragma unroll
    for (int r = 0; r < 4; ++r) ov[r] = (__bf16)(oacc[nd][r] * inv);
    *(bf16x4*)&orow[nd * 16 + g * 4] = ov;
  }
}

// ---------------------------------------------------------------------------
extern "C" void kernel_launch(void* const* d_in, const int* in_sizes, int n_in,
                              void* d_out, int out_size, void* d_ws, size_t ws_size,
                              hipStream_t stream) {
  (void)in_sizes; (void)n_in; (void)out_size; (void)ws_size;
  const float* X  = (const float*)d_in[0];
  const unsigned char* pm = (const unsigned char*)d_in[1];
  const float* Wq = (const float*)d_in[2];
  const float* Wk = (const float*)d_in[3];
  const float* Wv = (const float*)d_in[4];
  const float* Wo = (const float*)d_in[5];
  const float* qs = (const float*)d_in[6];
  const float* ks = (const float*)d_in[7];
  const float* pd = (const float*)d_in[8];
  float* out = (float*)d_out;

  char* ws = (char*)d_ws;
  int*    nm   = (int*)ws;                               // [0, 256)
  __bf16* Wqkv = (__bf16*)(ws + 256);                    // 3072x1024 (6MB)
  __bf16* Wob  = (__bf16*)(ws + 256 + 6291456);          // 1024x1024 (2MB)
  __bf16* Xb   = (__bf16*)(ws + 8388864);                // 4096x1024 (8MB)
  __bf16* QKV  = (__bf16*)(ws + 16777472);               // 4096x3072 (24MB, V cols unused)
  __bf16* Krb  = (__bf16*)(ws + 41943296);               // [b,h,s,d] (8MB)
  __bf16* Vtb  = (__bf16*)(ws + 50331904);               // [b,h,d,s] (8MB)
  float*  tab  = (float*)(ws + 58720512);                // RoPE table (256.25KB)
  float*  qmul = (float*)(ws + 58982912);                // 64 floats
  float*  kmul = (float*)(ws + 58983168);                // 64 floats
  __bf16* Qrb  = Xb;                                     // alias (Xb dead after gemm1)
  __bf16* Obuf = QKV;                                    // alias (QKV dead after rope)

  prep_kernel<<<8323, 256, 0, stream>>>(X, Wq, Wk, Wv, Wo, pm, qs, ks, pd,
                                        Xb, Wqkv, Wob, nm, tab, qmul, kmul);

  // QKV projection; Q/K rows -> QKV buffer, V -> transposed Vtb
  gemm_nt<1><<<dim3(24, 32), 256, 0, stream>>>(Xb, Wqkv, nullptr, QKV, Vtb, 3072, 1024);

  rope_rms<<<2048, 256, 0, stream>>>(QKV, Qrb, Krb, qmul, kmul, nm, tab);

  attn_fwd<<<1024, 256, 0, stream>>>(Qrb, Krb, Vtb, Obuf, nm);

  // out = Obuf @ Wo^T  (M=4096, N=1024, K=1024)
  gemm_nt<0><<<dim3(8, 32), 256, 0, stream>>>(Obuf, Wob, out, nullptr, nullptr, 1024, 1024);
}